// Round 5
// baseline (3719.305 us; speedup 1.0000x reference)
//
#include <hip/hip_runtime.h>
#include <hip/hip_bf16.h>
#include <hip/hip_cooperative_groups.h>
#include <math.h>

namespace cg = cooperative_groups;

namespace {

constexpr int kB = 128, kF = 2048, kH = 1024, kE = 512, kV = 16384, kT = 20;

typedef __attribute__((ext_vector_type(4))) float f32x4;
typedef __attribute__((ext_vector_type(8))) short bf16x8;

#define MFMA(a, b, c) __builtin_amdgcn_mfma_f32_16x16x32_bf16((a), (b), (c), 0, 0, 0)

__device__ __forceinline__ short f2bf(float f) {
  union { float f; unsigned u; } un;
  un.f = f;
  unsigned x = un.u;
  x += 0x7fffu + ((x >> 16) & 1u);
  return (short)(x >> 16);
}

__device__ __forceinline__ float bf2f(short s) {
  union { unsigned u; float f; } un;
  un.u = ((unsigned)(unsigned short)s) << 16;
  return un.f;
}

__device__ __forceinline__ float sigm(float x) { return 1.0f / (1.0f + __expf(-x)); }

__device__ __forceinline__ void cvt4(const float* __restrict__ s, short* __restrict__ d,
                                     long n4, long gid, long gs) {
  for (long i = gid; i < n4; i += gs) {
    float4 v = ((const float4*)s)[i];
    short4 o;
    o.x = f2bf(v.x); o.y = f2bf(v.y); o.z = f2bf(v.z); o.w = f2bf(v.w);
    ((short4*)d)[i] = o;
  }
}

// ---------------- prologue: fp32 -> bf16 weight conversion + e0 (fp32) ----------------
__global__ __launch_bounds__(256) void k_convert(
    const float* __restrict__ wout, const float* __restrict__ emb,
    const float* __restrict__ wih, const float* __restrict__ whh,
    const float* __restrict__ aw, const float* __restrict__ img,
    const float* __restrict__ sos,
    short* __restrict__ wout_b, short* __restrict__ emb_b,
    short* __restrict__ wih_b, short* __restrict__ whh_b,
    short* __restrict__ aw_b, short* __restrict__ img_b,
    float* __restrict__ e_f) {
  long gid = (long)blockIdx.x * blockDim.x + threadIdx.x;
  long gs = (long)gridDim.x * blockDim.x;
  cvt4(wout, wout_b, (long)kV * kH / 4, gid, gs);
  cvt4(emb, emb_b, (long)kE * kV / 4, gid, gs);
  cvt4(wih, wih_b, (long)3 * kH * kE / 4, gid, gs);
  cvt4(whh, whh_b, (long)3 * kH * kH / 4, gid, gs);
  cvt4(aw, aw_b, (long)kH * kF / 4, gid, gs);
  cvt4(img, img_b, (long)kB * kF / 4, gid, gs);
  for (long i = gid; i < kB * kE; i += gs) e_f[i] = sos[i & (kE - 1)];
}

// ---------------- h0 = img @ agent_w.T + agent_b ----------------
__global__ __launch_bounds__(256) void k_h0(const short* __restrict__ img_b,
                                            const short* __restrict__ aw_b,
                                            const float* __restrict__ ab,
                                            float* __restrict__ hf, short* __restrict__ hb) {
  int tid = threadIdx.x;
  int l = tid & 63, w = tid >> 6;
  int lr = l & 15, g = l >> 4, lk = g * 8;
  int col0 = blockIdx.x * 16;
  int row0 = w * 32;
  f32x4 acc[2] = {};
#pragma unroll 4
  for (int k0 = 0; k0 < kF; k0 += 32) {
    bf16x8 a0 = *(const bf16x8*)&img_b[(row0 + lr) * kF + k0 + lk];
    bf16x8 a1 = *(const bf16x8*)&img_b[(row0 + 16 + lr) * kF + k0 + lk];
    bf16x8 b = *(const bf16x8*)&aw_b[(size_t)(col0 + lr) * kF + k0 + lk];
    acc[0] = MFMA(a0, b, acc[0]);
    acc[1] = MFMA(a1, b, acc[1]);
  }
  int col = col0 + lr;
  float bias = ab[col];
#pragma unroll
  for (int mf = 0; mf < 2; ++mf)
#pragma unroll
    for (int j = 0; j < 4; ++j) {
      int row = row0 + mf * 16 + g * 4 + j;
      float v = acc[mf][j] + bias;
      hf[row * kH + col] = v;
      hb[row * kH + col] = f2bf(v);
    }
}

// ================= persistent cooperative main loop =================
// grid 256 x 512 thr (8 waves), 1 block/CU. Per step: 3 grid syncs.
__global__ __launch_bounds__(512, 2) void k_main(
    const short* __restrict__ wih_b, const short* __restrict__ whh_b,
    const float* __restrict__ bih, const float* __restrict__ bhh,
    const short* __restrict__ wout_b, const float* __restrict__ bout,
    const float* __restrict__ gum, const short* __restrict__ emb_b,
    float* __restrict__ e_f, float* __restrict__ hf,
    short* __restrict__ hb0, short* __restrict__ hb1,
    short* __restrict__ p_b, float* __restrict__ denom, float* __restrict__ out) {
  cg::grid_group gg = cg::this_grid();
  __shared__ f32x4 smem4[2080];  // A: 32KB gate partials | B: 2KB | C: 512B rd + 32KB x
  int bid = blockIdx.x, tid = threadIdx.x;
  int l = tid & 63, w = tid >> 6;
  int lr = l & 15, g = l >> 4, lk = g * 8;

  for (int t = 0; t < kT; ++t) {
    const short* hbp = (t & 1) ? hb1 : hb0;
    short* hbn = (t & 1) ? hb0 : hb1;
    const float* gum_t = gum + (size_t)t * kB * kV;

    // ---------- phase A: GRU (h = GRUCell(e, h)), 4-way K-split ----------
    {
      if (bid == 0 && tid < 32) {
        float4 z = {0.0f, 0.0f, 0.0f, 0.0f};
        *(float4*)&denom[tid * 4] = z;
      }
      int colt = bid >> 2, rq = bid & 3;
      int col0 = colt * 16;
      int rh = w & 1, kq = w >> 1;
      int row0 = rq * 32 + rh * 16;
      f32x4 pr = {}, pz = {}, pin = {}, phn = {};
      int ke0 = kq * 128;
#pragma unroll
      for (int ki = 0; ki < 4; ++ki) {
        int k0 = ke0 + ki * 32;
        float4 af0 = *(const float4*)&e_f[(row0 + lr) * kE + k0 + lk];
        float4 af1 = *(const float4*)&e_f[(row0 + lr) * kE + k0 + lk + 4];
        bf16x8 a;
        a[0] = f2bf(af0.x); a[1] = f2bf(af0.y); a[2] = f2bf(af0.z); a[3] = f2bf(af0.w);
        a[4] = f2bf(af1.x); a[5] = f2bf(af1.y); a[6] = f2bf(af1.z); a[7] = f2bf(af1.w);
        bf16x8 br = *(const bf16x8*)&wih_b[(size_t)(col0 + lr) * kE + k0 + lk];
        bf16x8 bz = *(const bf16x8*)&wih_b[(size_t)(kH + col0 + lr) * kE + k0 + lk];
        bf16x8 bn = *(const bf16x8*)&wih_b[(size_t)(2 * kH + col0 + lr) * kE + k0 + lk];
        pr = MFMA(a, br, pr);
        pz = MFMA(a, bz, pz);
        pin = MFMA(a, bn, pin);
      }
      int kh0 = kq * 256;
#pragma unroll
      for (int ki = 0; ki < 8; ++ki) {
        int k0 = kh0 + ki * 32;
        bf16x8 a = *(const bf16x8*)&hbp[(row0 + lr) * kH + k0 + lk];
        bf16x8 br = *(const bf16x8*)&whh_b[(size_t)(col0 + lr) * kH + k0 + lk];
        bf16x8 bz = *(const bf16x8*)&whh_b[(size_t)(kH + col0 + lr) * kH + k0 + lk];
        bf16x8 bn = *(const bf16x8*)&whh_b[(size_t)(2 * kH + col0 + lr) * kH + k0 + lk];
        pr = MFMA(a, br, pr);
        pz = MFMA(a, bz, pz);
        phn = MFMA(a, bn, phn);
      }
      // partials -> LDS: [gate][rh][kq][lane]
      smem4[((0 * 2 + rh) * 4 + kq) * 64 + l] = pr;
      smem4[((1 * 2 + rh) * 4 + kq) * 64 + l] = pz;
      smem4[((2 * 2 + rh) * 4 + kq) * 64 + l] = pin;
      smem4[((3 * 2 + rh) * 4 + kq) * 64 + l] = phn;
      __syncthreads();
      if (w < 2) {
        int rh2 = w;
        int row0e = rq * 32 + rh2 * 16;
        f32x4 rs = {}, zs = {}, is = {}, hs = {};
#pragma unroll
        for (int q = 0; q < 4; ++q) {
          rs += smem4[((0 * 2 + rh2) * 4 + q) * 64 + l];
          zs += smem4[((1 * 2 + rh2) * 4 + q) * 64 + l];
          is += smem4[((2 * 2 + rh2) * 4 + q) * 64 + l];
          hs += smem4[((3 * 2 + rh2) * 4 + q) * 64 + l];
        }
        int col = col0 + lr;
        float bihr = bih[col], bhhr = bhh[col];
        float bihz = bih[kH + col], bhhz = bhh[kH + col];
        float bihn = bih[2 * kH + col], bhhn = bhh[2 * kH + col];
#pragma unroll
        for (int j = 0; j < 4; ++j) {
          int row = row0e + g * 4 + j;
          float r = sigm(rs[j] + bihr + bhhr);
          float z = sigm(zs[j] + bihz + bhhz);
          float nn = tanhf(is[j] + bihn + r * (hs[j] + bhhn));
          float hv = (1.0f - z) * nn + z * hf[row * kH + col];
          hf[row * kH + col] = hv;
          hbn[row * kH + col] = f2bf(hv);
        }
      }
    }
    gg.sync();

    // ---------- phase B: logits GEMM + p = exp(logit+gumbel) + denom atomics ----------
    {
      int gi = bid * 512 + tid;
      if (gi < kB * kE) e_f[gi] = 0.0f;  // zero e accumulator for phase C
      int wm = w >> 2, wn = w & 3;
      int col = bid * 64 + wn * 16 + lr;
      int row0 = wm * 64;
      float gmr[16];
#pragma unroll
      for (int mf = 0; mf < 4; ++mf)
#pragma unroll
        for (int j = 0; j < 4; ++j)
          gmr[mf * 4 + j] = gum_t[(size_t)(row0 + mf * 16 + g * 4 + j) * kV + col];
      float bo = bout[col];
      const short* Bp = &wout_b[(size_t)col * kH + lk];
      f32x4 acc[4] = {};
      bf16x8 brg[8], arg[2][4];
#pragma unroll
      for (int k = 0; k < 8; ++k) brg[k] = *(const bf16x8*)(Bp + k * 32);
#pragma unroll
      for (int k = 0; k < 2; ++k)
#pragma unroll
        for (int mf = 0; mf < 4; ++mf)
          arg[k][mf] = *(const bf16x8*)&hbn[(row0 + mf * 16 + lr) * kH + k * 32 + lk];
#pragma unroll
      for (int k = 0; k < 32; ++k) {
        acc[0] = MFMA(arg[k & 1][0], brg[k & 7], acc[0]);
        acc[1] = MFMA(arg[k & 1][1], brg[k & 7], acc[1]);
        acc[2] = MFMA(arg[k & 1][2], brg[k & 7], acc[2]);
        acc[3] = MFMA(arg[k & 1][3], brg[k & 7], acc[3]);
        if (k < 24) brg[k & 7] = *(const bf16x8*)(Bp + (k + 8) * 32);
        if (k < 30) {
#pragma unroll
          for (int mf = 0; mf < 4; ++mf)
            arg[k & 1][mf] =
                *(const bf16x8*)&hbn[(row0 + mf * 16 + lr) * kH + (k + 2) * 32 + lk];
        }
      }
      float* ls = (float*)smem4;  // [wm][wn][64]
      float p[16];
#pragma unroll
      for (int i = 0; i < 16; ++i) p[i] = __expf(acc[i >> 2][i & 3] + bo + gmr[i]);
#pragma unroll
      for (int i = 0; i < 16; ++i) {
        int rl = (i >> 2) * 16 + g * 4 + (i & 3);
        p_b[(size_t)(row0 + rl) * kV + col] = f2bf(p[i]);
      }
#pragma unroll
      for (int i = 0; i < 16; ++i) {
        float s = p[i];
#pragma unroll
        for (int sf = 1; sf < 16; sf <<= 1) s += __shfl_xor(s, sf, 64);
        if (lr == 0) ls[((wm * 4 + wn) * 64) + (i >> 2) * 16 + g * 4 + (i & 3)] = s;
      }
      __syncthreads();
      if (tid < 128) {
        int row = tid, wmm = tid >> 6, rl = tid & 63;
        float sb = ls[(wmm * 4 + 0) * 64 + rl] + ls[(wmm * 4 + 1) * 64 + rl] +
                   ls[(wmm * 4 + 2) * 64 + rl] + ls[(wmm * 4 + 3) * 64 + rl];
        atomicAdd(&denom[row], sb);
      }
    }
    gg.sync();

    // ---------- phase C: blocks 0-127 e-GEMM (atomic into e_f); 128-255 out-write ----------
    if (bid < 128) {
      int wm = w >> 2, wn = w & 3;
      int kc = bid >> 3, et = bid & 7;
      int kbase = kc * 1024;
      int colB = et * 64 + wn * 16 + lr;
      float* s_rd = (float*)smem4;          // 512 B
      char* xs = (char*)(smem4 + 32);       // 32 KB swizzled x tile
      if (tid < kB) s_rd[tid] = 1.0f / denom[tid];
      int colg = tid & 15, rrow = tid >> 4;
      f32x4 acc[4] = {};
      __syncthreads();
      for (int s = 0; s < 8; ++s) {
        if (s) __syncthreads();
#pragma unroll
        for (int rr = 0; rr < 4; ++rr) {
          int row = rr * 32 + rrow;
          int cb = s * 128 + colg * 8;
          bf16x8 p8 = *(const bf16x8*)&p_b[(size_t)row * kV + kbase + cb];
          float scl = s_rd[row];
          bf16x8 xv;
#pragma unroll
          for (int i = 0; i < 8; ++i) xv[i] = f2bf(bf2f(p8[i]) * scl);
          unsigned off = (unsigned)(row * 256 + colg * 16) ^ ((row & 7) << 4);
          *(bf16x8*)(xs + off) = xv;
        }
        __syncthreads();
#pragma unroll
        for (int kk = 0; kk < 4; ++kk) {
          bf16x8 b =
              *(const bf16x8*)&emb_b[(size_t)colB * kV + kbase + s * 128 + kk * 32 + lk];
#pragma unroll
          for (int mf = 0; mf < 4; ++mf) {
            int rowa = wm * 64 + mf * 16 + lr;
            unsigned off = (unsigned)(rowa * 256 + (kk * 32 + lk) * 2) ^ ((rowa & 7) << 4);
            bf16x8 a = *(const bf16x8*)(xs + off);
            acc[mf] = MFMA(a, b, acc[mf]);
          }
        }
      }
#pragma unroll
      for (int mf = 0; mf < 4; ++mf)
#pragma unroll
        for (int j = 0; j < 4; ++j) {
          int row = wm * 64 + mf * 16 + g * 4 + j;
          atomicAdd(&e_f[row * kE + et * 64 + wn * 16 + lr], acc[mf][j]);
        }
    } else {
      int r = bid - 128;
      float rd = 1.0f / denom[r];
      const short* pr = &p_b[(size_t)r * kV + tid * 32];
      float* orow = &out[(size_t)r * (kT * kV) + (size_t)t * kV + tid * 32];
#pragma unroll
      for (int jj = 0; jj < 4; ++jj) {
        bf16x8 p8 = *(const bf16x8*)(pr + jj * 8);
        float4 o0, o1;
        o0.x = bf2f(p8[0]) * rd; o0.y = bf2f(p8[1]) * rd;
        o0.z = bf2f(p8[2]) * rd; o0.w = bf2f(p8[3]) * rd;
        o1.x = bf2f(p8[4]) * rd; o1.y = bf2f(p8[5]) * rd;
        o1.z = bf2f(p8[6]) * rd; o1.w = bf2f(p8[7]) * rd;
        *(float4*)(orow + jj * 8) = o0;
        *(float4*)(orow + jj * 8 + 4) = o1;
      }
    }
    if (t < kT - 1) gg.sync();
  }
}

}  // namespace

extern "C" void kernel_launch(void* const* d_in, const int* in_sizes, int n_in,
                              void* d_out, int out_size, void* d_ws, size_t ws_size,
                              hipStream_t stream) {
  const float* img = (const float*)d_in[0];
  const float* aw = (const float*)d_in[1];
  const float* ab = (const float*)d_in[2];
  const float* wih = (const float*)d_in[3];
  const float* whh = (const float*)d_in[4];
  const float* bih = (const float*)d_in[5];
  const float* bhh = (const float*)d_in[6];
  const float* wout = (const float*)d_in[7];
  const float* bout = (const float*)d_in[8];
  const float* emb = (const float*)d_in[9];
  const float* sos = (const float*)d_in[10];
  const float* gum = (const float*)d_in[11];
  float* out = (float*)d_out;
  char* ws = (char*)d_ws;

  short* wout_b = (short*)(ws + 0);            // 33554432
  short* emb_b = (short*)(ws + 33554432);      // 16777216
  short* wih_b = (short*)(ws + 50331648);      // 3145728
  short* whh_b = (short*)(ws + 53477376);      // 6291456
  short* aw_b = (short*)(ws + 59768832);       // 4194304
  short* img_b = (short*)(ws + 63963136);      // 524288
  float* hf = (float*)(ws + 64487424);         // 524288 (fp32 h, in-place)
  short* hb0 = (short*)(ws + 65011712);        // 262144
  short* hb1 = (short*)(ws + 65273856);        // 262144
  short* p_b = (short*)(ws + 65536000);        // 4194304
  float* denom = (float*)(ws + 69730304);      // 4096 (128 used)
  float* e_f = (float*)(ws + 69734400);        // 262144 (fp32 e accumulator)

  k_convert<<<2048, 256, 0, stream>>>(wout, emb, wih, whh, aw, img, sos, wout_b, emb_b,
                                      wih_b, whh_b, aw_b, img_b, e_f);
  k_h0<<<64, 256, 0, stream>>>(img_b, aw_b, ab, hf, hb0);

  void* args[] = {(void*)&wih_b, (void*)&whh_b, (void*)&bih,   (void*)&bhh,
                  (void*)&wout_b, (void*)&bout, (void*)&gum,   (void*)&emb_b,
                  (void*)&e_f,    (void*)&hf,   (void*)&hb0,   (void*)&hb1,
                  (void*)&p_b,    (void*)&denom, (void*)&out};
  hipLaunchCooperativeKernel((void*)k_main, dim3(256), dim3(512), args, 0, stream);
}

// Round 6
// 1896.413 us; speedup vs baseline: 1.9612x; 1.9612x over previous
//
#include <hip/hip_runtime.h>
#include <hip/hip_bf16.h>
#include <math.h>

namespace {

constexpr int kB = 128, kF = 2048, kH = 1024, kE = 512, kV = 16384, kT = 20;

typedef __attribute__((ext_vector_type(4))) float f32x4;
typedef __attribute__((ext_vector_type(8))) short bf16x8;

#define MFMA(a, b, c) __builtin_amdgcn_mfma_f32_16x16x32_bf16((a), (b), (c), 0, 0, 0)

__device__ __forceinline__ short f2bf(float f) {
  union { float f; unsigned u; } un;
  un.f = f;
  unsigned x = un.u;
  x += 0x7fffu + ((x >> 16) & 1u);
  return (short)(x >> 16);
}

__device__ __forceinline__ float bf2f(short s) {
  union { unsigned u; float f; } un;
  un.u = ((unsigned)(unsigned short)s) << 16;
  return un.f;
}

__device__ __forceinline__ float sigm(float x) { return 1.0f / (1.0f + __expf(-x)); }

__device__ __forceinline__ void cvt4(const float* __restrict__ s, short* __restrict__ d,
                                     long n4, long gid, long gs) {
  for (long i = gid; i < n4; i += gs) {
    float4 v = ((const float4*)s)[i];
    short4 o;
    o.x = f2bf(v.x); o.y = f2bf(v.y); o.z = f2bf(v.z); o.w = f2bf(v.w);
    ((short4*)d)[i] = o;
  }
}

// ---------------- prologue: fp32 -> bf16 weight conversion + e0 (fp32) ----------------
__global__ __launch_bounds__(256) void k_convert(
    const float* __restrict__ wout, const float* __restrict__ emb,
    const float* __restrict__ wih, const float* __restrict__ whh,
    const float* __restrict__ aw, const float* __restrict__ img,
    const float* __restrict__ sos,
    short* __restrict__ wout_b, short* __restrict__ emb_b,
    short* __restrict__ wih_b, short* __restrict__ whh_b,
    short* __restrict__ aw_b, short* __restrict__ img_b,
    float* __restrict__ e_f) {
  long gid = (long)blockIdx.x * blockDim.x + threadIdx.x;
  long gs = (long)gridDim.x * blockDim.x;
  cvt4(wout, wout_b, (long)kV * kH / 4, gid, gs);
  cvt4(emb, emb_b, (long)kE * kV / 4, gid, gs);
  cvt4(wih, wih_b, (long)3 * kH * kE / 4, gid, gs);
  cvt4(whh, whh_b, (long)3 * kH * kH / 4, gid, gs);
  cvt4(aw, aw_b, (long)kH * kF / 4, gid, gs);
  cvt4(img, img_b, (long)kB * kF / 4, gid, gs);
  for (long i = gid; i < kB * kE; i += gs) e_f[i] = sos[i & (kE - 1)];
}

// ---------------- h0 = img @ agent_w.T + agent_b ----------------
__global__ __launch_bounds__(256) void k_h0(const short* __restrict__ img_b,
                                            const short* __restrict__ aw_b,
                                            const float* __restrict__ ab,
                                            float* __restrict__ hf, short* __restrict__ hb) {
  int tid = threadIdx.x;
  int l = tid & 63, w = tid >> 6;
  int lr = l & 15, g = l >> 4, lk = g * 8;
  int col0 = blockIdx.x * 16;
  int row0 = w * 32;
  f32x4 acc[2] = {};
#pragma unroll 4
  for (int k0 = 0; k0 < kF; k0 += 32) {
    bf16x8 a0 = *(const bf16x8*)&img_b[(row0 + lr) * kF + k0 + lk];
    bf16x8 a1 = *(const bf16x8*)&img_b[(row0 + 16 + lr) * kF + k0 + lk];
    bf16x8 b = *(const bf16x8*)&aw_b[(size_t)(col0 + lr) * kF + k0 + lk];
    acc[0] = MFMA(a0, b, acc[0]);
    acc[1] = MFMA(a1, b, acc[1]);
  }
  int col = col0 + lr;
  float bias = ab[col];
#pragma unroll
  for (int mf = 0; mf < 2; ++mf)
#pragma unroll
    for (int j = 0; j < 4; ++j) {
      int row = row0 + mf * 16 + g * 4 + j;
      float v = acc[mf][j] + bias;
      hf[row * kH + col] = v;
      hb[row * kH + col] = f2bf(v);
    }
}

// ---------------- GRU cell + overlapped out-write of step t-1 ----------------
// grid 256 = 64 col-tiles x 4 row-quarters; 512 thr.
// Waves 0-3: GRU GEMM, wave (rh, kq) = 16-row half x K-half, LDS combine.
// Waves 4-7: write out(t-1) = p_prev * (1/denom_prev) with nontemporal stores.
__global__ __launch_bounds__(512) void k_gru(
    const float* __restrict__ e_f, const short* __restrict__ hb_prev,
    float* __restrict__ hf,
    const short* __restrict__ wih_b, const short* __restrict__ whh_b,
    const float* __restrict__ bih, const float* __restrict__ bhh,
    short* __restrict__ hb_next, float* __restrict__ denom_cur,
    const short* __restrict__ p_prev, const float* __restrict__ denom_prev,
    float* __restrict__ out_prev) {
  int tid = threadIdx.x, bid = blockIdx.x;
  int l = tid & 63, w = tid >> 6;
  int lr = l & 15, g = l >> 4, lk = g * 8;
  __shared__ f32x4 part[4][2][2][64];  // [comp][rh][kq][lane], 16 KB
  int colt = bid >> 2, rq = bid & 3;
  int col0 = colt * 16;
  if (w < 4) {
    int rh = w & 1, kq = w >> 1;
    int row0 = rq * 32 + rh * 16;
    if (bid == 0 && tid < 32) {
      f32x4 z = {0.0f, 0.0f, 0.0f, 0.0f};
      *(f32x4*)&denom_cur[tid * 4] = z;
    }
    f32x4 ar = {}, az = {}, ain = {}, ahn = {};
    if (kq == 0) {
#pragma unroll 4
      for (int ki = 0; ki < 16; ++ki) {
        int k0 = ki * 32;
        float4 af0 = *(const float4*)&e_f[(row0 + lr) * kE + k0 + lk];
        float4 af1 = *(const float4*)&e_f[(row0 + lr) * kE + k0 + lk + 4];
        bf16x8 a;
        a[0] = f2bf(af0.x); a[1] = f2bf(af0.y); a[2] = f2bf(af0.z); a[3] = f2bf(af0.w);
        a[4] = f2bf(af1.x); a[5] = f2bf(af1.y); a[6] = f2bf(af1.z); a[7] = f2bf(af1.w);
        bf16x8 br = *(const bf16x8*)&wih_b[(size_t)(col0 + lr) * kE + k0 + lk];
        bf16x8 bz = *(const bf16x8*)&wih_b[(size_t)(kH + col0 + lr) * kE + k0 + lk];
        bf16x8 bn = *(const bf16x8*)&wih_b[(size_t)(2 * kH + col0 + lr) * kE + k0 + lk];
        ar = MFMA(a, br, ar);
        az = MFMA(a, bz, az);
        ain = MFMA(a, bn, ain);
      }
#pragma unroll 4
      for (int ki = 0; ki < 8; ++ki) {
        int k0 = ki * 32;
        bf16x8 a = *(const bf16x8*)&hb_prev[(row0 + lr) * kH + k0 + lk];
        bf16x8 br = *(const bf16x8*)&whh_b[(size_t)(col0 + lr) * kH + k0 + lk];
        bf16x8 bz = *(const bf16x8*)&whh_b[(size_t)(kH + col0 + lr) * kH + k0 + lk];
        bf16x8 bn = *(const bf16x8*)&whh_b[(size_t)(2 * kH + col0 + lr) * kH + k0 + lk];
        ar = MFMA(a, br, ar);
        az = MFMA(a, bz, az);
        ahn = MFMA(a, bn, ahn);
      }
    } else {
#pragma unroll 4
      for (int ki = 0; ki < 24; ++ki) {
        int k0 = 256 + ki * 32;
        bf16x8 a = *(const bf16x8*)&hb_prev[(row0 + lr) * kH + k0 + lk];
        bf16x8 br = *(const bf16x8*)&whh_b[(size_t)(col0 + lr) * kH + k0 + lk];
        bf16x8 bz = *(const bf16x8*)&whh_b[(size_t)(kH + col0 + lr) * kH + k0 + lk];
        bf16x8 bn = *(const bf16x8*)&whh_b[(size_t)(2 * kH + col0 + lr) * kH + k0 + lk];
        ar = MFMA(a, br, ar);
        az = MFMA(a, bz, az);
        ahn = MFMA(a, bn, ahn);
      }
    }
    part[0][rh][kq][l] = ar;
    part[1][rh][kq][l] = az;
    part[2][rh][kq][l] = ain;
    part[3][rh][kq][l] = ahn;
  } else if (out_prev != nullptr) {
    // out-write for previous step: x = p * (1/denom), nontemporal
    int r = bid >> 1, halfc = bid & 1;
    float rd = 1.0f / denom_prev[r];
    int coff = halfc * 8192 + (w - 4) * 2048 + l * 32;
    const short* pr = p_prev + (size_t)r * kV + coff;
    float* orow = out_prev + (size_t)r * (kT * kV) + coff;
#pragma unroll
    for (int jj = 0; jj < 4; ++jj) {
      bf16x8 p8 = *(const bf16x8*)(pr + jj * 8);
      f32x4 o0, o1;
      o0[0] = bf2f(p8[0]) * rd; o0[1] = bf2f(p8[1]) * rd;
      o0[2] = bf2f(p8[2]) * rd; o0[3] = bf2f(p8[3]) * rd;
      o1[0] = bf2f(p8[4]) * rd; o1[1] = bf2f(p8[5]) * rd;
      o1[2] = bf2f(p8[6]) * rd; o1[3] = bf2f(p8[7]) * rd;
      __builtin_nontemporal_store(o0, (f32x4*)(orow + jj * 8));
      __builtin_nontemporal_store(o1, (f32x4*)(orow + jj * 8 + 4));
    }
  }
  __syncthreads();
  if (w < 2) {
    int rh2 = w;
    int row0e = rq * 32 + rh2 * 16;
    f32x4 rs = part[0][rh2][0][l] + part[0][rh2][1][l];
    f32x4 zs = part[1][rh2][0][l] + part[1][rh2][1][l];
    f32x4 is = part[2][rh2][0][l] + part[2][rh2][1][l];
    f32x4 hs = part[3][rh2][0][l] + part[3][rh2][1][l];
    int col = col0 + lr;
    float bihr = bih[col], bhhr = bhh[col];
    float bihz = bih[kH + col], bhhz = bhh[kH + col];
    float bihn = bih[2 * kH + col], bhhn = bhh[2 * kH + col];
#pragma unroll
    for (int j = 0; j < 4; ++j) {
      int row = row0e + g * 4 + j;
      float r = sigm(rs[j] + bihr + bhhr);
      float z = sigm(zs[j] + bihz + bhhz);
      float nn = tanhf(is[j] + bihn + r * (hs[j] + bhhn));
      float hv = (1.0f - z) * nn + z * hf[row * kH + col];
      hf[row * kH + col] = hv;
      hb_next[row * kH + col] = f2bf(hv);
    }
  }
}

// ---------------- logits GEMM + p = exp(logit+gumbel) + row-sum atomics ----------------
// grid 256 (V/64 tiles), 512 thr; waves 2M x 4N (wave 64r x 16c).
// No max subtraction: |logit+gumbel| << 88, exp() safe in fp32 (exact after division).
// Ring prefetch (B 8-deep, A 2-deep); gumbel loads nontemporal; zeroes e_f for k_e.
__global__ __launch_bounds__(512) void k_logits(
    const short* __restrict__ h_b, const short* __restrict__ wout_b,
    const float* __restrict__ bout, const float* __restrict__ gum_t,
    short* __restrict__ p_b, float* __restrict__ denom, float* __restrict__ e_f) {
  int tid = threadIdx.x;
  int l = tid & 63, w = tid >> 6;
  int lr = l & 15, g = l >> 4, lk = g * 8;
  int wm = w >> 2, wn = w & 3;
  int n0 = blockIdx.x * 64;
  int col = n0 + wn * 16 + lr;
  int row0 = wm * 64;
  int gi = blockIdx.x * 512 + tid;
  if (gi < kB * kE) e_f[gi] = 0.0f;  // zero e accumulator for k_e atomics
  float gmr[16];
#pragma unroll
  for (int mf = 0; mf < 4; ++mf)
#pragma unroll
    for (int j = 0; j < 4; ++j)
      gmr[mf * 4 + j] = __builtin_nontemporal_load(
          &gum_t[(size_t)(row0 + mf * 16 + g * 4 + j) * kV + col]);
  float bo = bout[col];
  const short* Bp = &wout_b[(size_t)col * kH + lk];
  f32x4 acc[4] = {};
  bf16x8 brg[8], arg[2][4];
#pragma unroll
  for (int k = 0; k < 8; ++k) brg[k] = *(const bf16x8*)(Bp + k * 32);
#pragma unroll
  for (int k = 0; k < 2; ++k)
#pragma unroll
    for (int mf = 0; mf < 4; ++mf)
      arg[k][mf] = *(const bf16x8*)&h_b[(row0 + mf * 16 + lr) * kH + k * 32 + lk];
#pragma unroll
  for (int k = 0; k < 32; ++k) {
    acc[0] = MFMA(arg[k & 1][0], brg[k & 7], acc[0]);
    acc[1] = MFMA(arg[k & 1][1], brg[k & 7], acc[1]);
    acc[2] = MFMA(arg[k & 1][2], brg[k & 7], acc[2]);
    acc[3] = MFMA(arg[k & 1][3], brg[k & 7], acc[3]);
    if (k < 24) brg[k & 7] = *(const bf16x8*)(Bp + (k + 8) * 32);
    if (k < 30) {
#pragma unroll
      for (int mf = 0; mf < 4; ++mf)
        arg[k & 1][mf] =
            *(const bf16x8*)&h_b[(row0 + mf * 16 + lr) * kH + (k + 2) * 32 + lk];
    }
  }
  __shared__ float ls[2][4][64];
  float p[16];
#pragma unroll
  for (int i = 0; i < 16; ++i) p[i] = __expf(acc[i >> 2][i & 3] + bo + gmr[i]);
#pragma unroll
  for (int i = 0; i < 16; ++i) {
    int rl = (i >> 2) * 16 + g * 4 + (i & 3);
    p_b[(size_t)(row0 + rl) * kV + col] = f2bf(p[i]);
  }
#pragma unroll
  for (int i = 0; i < 16; ++i) {
    float s = p[i];
#pragma unroll
    for (int sf = 1; sf < 16; sf <<= 1) s += __shfl_xor(s, sf, 64);
    if (lr == 0) ls[wm][wn][(i >> 2) * 16 + g * 4 + (i & 3)] = s;
  }
  __syncthreads();
  if (tid < 128) {
    int row = tid, wmm = tid >> 6, rl = tid & 63;
    float sb = ls[wmm][0][rl] + ls[wmm][1][rl] + ls[wmm][2][rl] + ls[wmm][3][rl];
    atomicAdd(&denom[row], sb);
  }
}

// ---------------- e-partial GEMM: e_f += x[:, kc] @ emb[:, kc].T (atomic) ----------------
// grid 256 = kc(32 K-chunks of 512) x et(8 E-tiles of 64); 512 thr, waves 2M x 4N.
// x = p * (1/denom[row]) staged into XOR-swizzled LDS bf16.
__global__ __launch_bounds__(512) void k_e(
    const short* __restrict__ p_b, const float* __restrict__ denom,
    const short* __restrict__ emb_b, float* __restrict__ e_f) {
  int tid = threadIdx.x;
  int l = tid & 63, w = tid >> 6;
  int lr = l & 15, g = l >> 4, lk = g * 8;
  int wm = w >> 2, wn = w & 3;
  int kc = blockIdx.x >> 3, et = blockIdx.x & 7;
  int kbase = kc * 512;
  int colB = et * 64 + wn * 16 + lr;
  __shared__ float s_rd[kB];
  if (tid < kB) s_rd[tid] = 1.0f / denom[tid];
  __shared__ bf16x8 xs8[2048];  // 128 rows x 128 cols bf16, XOR-swizzled
  char* xs = (char*)xs8;
  int colg = tid & 15, rrow = tid >> 4;
  f32x4 acc[4] = {};
  __syncthreads();
  for (int s = 0; s < 4; ++s) {
    if (s) __syncthreads();
#pragma unroll
    for (int rr = 0; rr < 4; ++rr) {
      int row = rr * 32 + rrow;
      int cb = s * 128 + colg * 8;
      bf16x8 p8 = *(const bf16x8*)&p_b[(size_t)row * kV + kbase + cb];
      float scl = s_rd[row];
      bf16x8 xv;
#pragma unroll
      for (int i = 0; i < 8; ++i) xv[i] = f2bf(bf2f(p8[i]) * scl);
      unsigned off = (unsigned)(row * 256 + colg * 16) ^ ((row & 7) << 4);
      *(bf16x8*)(xs + off) = xv;
    }
    __syncthreads();
#pragma unroll
    for (int kk = 0; kk < 4; ++kk) {
      bf16x8 b = *(const bf16x8*)&emb_b[(size_t)colB * kV + kbase + s * 128 + kk * 32 + lk];
#pragma unroll
      for (int mf = 0; mf < 4; ++mf) {
        int rowa = wm * 64 + mf * 16 + lr;
        unsigned off = (unsigned)(rowa * 256 + (kk * 32 + lk) * 2) ^ ((rowa & 7) << 4);
        bf16x8 a = *(const bf16x8*)(xs + off);
        acc[mf] = MFMA(a, b, acc[mf]);
      }
    }
  }
#pragma unroll
  for (int mf = 0; mf < 4; ++mf)
#pragma unroll
    for (int j = 0; j < 4; ++j) {
      int row = wm * 64 + mf * 16 + g * 4 + j;
      atomicAdd(&e_f[row * kE + et * 64 + wn * 16 + lr], acc[mf][j]);
    }
}

// ---------------- epilogue: write out for the final step ----------------
__global__ __launch_bounds__(256) void k_out(const short* __restrict__ p_b,
                                             const float* __restrict__ denom,
                                             float* __restrict__ outp) {
  int tid = threadIdx.x, bid = blockIdx.x;
  int r = bid >> 1, halfc = bid & 1;
  float rd = 1.0f / denom[r];
  int coff = halfc * 8192 + tid * 32;
  const short* pr = p_b + (size_t)r * kV + coff;
  float* orow = outp + (size_t)r * (kT * kV) + coff;
#pragma unroll
  for (int jj = 0; jj < 4; ++jj) {
    bf16x8 p8 = *(const bf16x8*)(pr + jj * 8);
    f32x4 o0, o1;
    o0[0] = bf2f(p8[0]) * rd; o0[1] = bf2f(p8[1]) * rd;
    o0[2] = bf2f(p8[2]) * rd; o0[3] = bf2f(p8[3]) * rd;
    o1[0] = bf2f(p8[4]) * rd; o1[1] = bf2f(p8[5]) * rd;
    o1[2] = bf2f(p8[6]) * rd; o1[3] = bf2f(p8[7]) * rd;
    __builtin_nontemporal_store(o0, (f32x4*)(orow + jj * 8));
    __builtin_nontemporal_store(o1, (f32x4*)(orow + jj * 8 + 4));
  }
}

}  // namespace

extern "C" void kernel_launch(void* const* d_in, const int* in_sizes, int n_in,
                              void* d_out, int out_size, void* d_ws, size_t ws_size,
                              hipStream_t stream) {
  const float* img = (const float*)d_in[0];
  const float* aw = (const float*)d_in[1];
  const float* ab = (const float*)d_in[2];
  const float* wih = (const float*)d_in[3];
  const float* whh = (const float*)d_in[4];
  const float* bih = (const float*)d_in[5];
  const float* bhh = (const float*)d_in[6];
  const float* wout = (const float*)d_in[7];
  const float* bout = (const float*)d_in[8];
  const float* emb = (const float*)d_in[9];
  const float* sos = (const float*)d_in[10];
  const float* gum = (const float*)d_in[11];
  float* out = (float*)d_out;
  char* ws = (char*)d_ws;

  short* wout_b = (short*)(ws + 0);            // 33554432
  short* emb_b = (short*)(ws + 33554432);      // 16777216
  short* wih_b = (short*)(ws + 50331648);      // 3145728
  short* whh_b = (short*)(ws + 53477376);      // 6291456
  short* aw_b = (short*)(ws + 59768832);       // 4194304
  short* img_b = (short*)(ws + 63963136);      // 524288
  float* hf = (float*)(ws + 64487424);         // 524288 (fp32 h, in-place)
  short* hb0 = (short*)(ws + 65011712);        // 262144
  short* hb1 = (short*)(ws + 65273856);        // 262144
  short* p_b = (short*)(ws + 65536000);        // 4194304
  float* denoms = (float*)(ws + 69730304);     // 2048 (2 x 256 floats)
  float* e_f = (float*)(ws + 69732352);        // 262144 (fp32 e accumulator)

  short* hb[2] = {hb0, hb1};

  k_convert<<<2048, 256, 0, stream>>>(wout, emb, wih, whh, aw, img, sos, wout_b, emb_b,
                                      wih_b, whh_b, aw_b, img_b, e_f);
  k_h0<<<64, 256, 0, stream>>>(img_b, aw_b, ab, hf, hb[0]);
  for (int t = 0; t < kT; ++t) {
    int rp = t & 1, wp = rp ^ 1;
    float* denomC = denoms + (t & 1) * 256;
    float* denomP = denoms + ((t & 1) ^ 1) * 256;
    float* out_prev = (t == 0) ? nullptr : out + (size_t)(t - 1) * kV;
    k_gru<<<256, 512, 0, stream>>>(e_f, hb[rp], hf, wih_b, whh_b, bih, bhh, hb[wp],
                                   denomC, p_b, denomP, out_prev);
    k_logits<<<256, 512, 0, stream>>>(hb[wp], wout_b, bout, gum + (size_t)t * kB * kV,
                                      p_b, denomC, e_f);
    k_e<<<256, 512, 0, stream>>>(p_b, denomC, emb_b, e_f);
  }
  k_out<<<256, 256, 0, stream>>>(p_b, denoms + 256, out + (size_t)(kT - 1) * kV);
}